// Round 3
// baseline (330.808 us; speedup 1.0000x reference)
//
#include <hip/hip_runtime.h>

// Two-layer bidirectional LSTM, S=512, B=8192, I=3, H=5.
// R19 = R18 meet-in-the-middle with the phase-2 output-pointer fix:
// op now starts at s=256 (fwd) / s=255 (bwd) -- the first row phase 2
// actually writes -- instead of the t=0 position (R18 wrote every out
// row at its mirrored timestep; absmax 0.277).
// Structure: layer1 wave owns 6 b-values x BOTH dirs (rows 0-5 fwd,
// 6-11 bwd). Phase1 (t=0..255): both dirs stash h (fp16) -- t<208 in
// LDS (24.9KB -> 6 blocks/CU), t>=208 in an 8.4MB global spill.
// Phase2 (t=256..511): fwd live at s=t pairs with stashed bwd h[t];
// bwd live at s=511-t pairs with stashed fwd. Each lane writes 2
// dwords -> 240B contiguous full-sector out runs; kills the 2x RMW
// write inflation of interleaved [S][B][10] halves.
// Layer0 unchanged from R17 (clean 144B plane writes).
// Carried: unit-per-lane, fp16 ws planes, fdot2 x-dots, depth-4/8
// rotating prefetch, sched_barrier after loads, waves_per_eu(1,2).

constexpr int S_ = 512;
constexpr int B_ = 8192;
constexpr int NROW = 16384;    // 2 dirs * 8192

constexpr int GD1  = 1366;         // layer1 grid = ceil(8192/6)
constexpr int TL   = 208;          // phi1 steps resident in LDS
constexpr int GSTR = GD1 * 64;     // spill stride per step (shorts)

constexpr float L2E  = 1.4426950408889634f;   // log2(e)
constexpr float T2E  = 2.8853900817779268f;   // 2*log2(e)
constexpr float IT2E = 0.34657359027997264f;  // 1/(2*log2(e))

typedef _Float16 v2h __attribute__((ext_vector_type(2)));

__device__ __forceinline__ float dot2h(v2h a, v2h b, float c) {
#if __has_builtin(__builtin_amdgcn_fdot2)
    return __builtin_amdgcn_fdot2(a, b, c, false);
#else
    return fmaf((float)a[0], (float)b[0], fmaf((float)a[1], (float)b[1], c));
#endif
}

__device__ __forceinline__ float rcp_(float x) { return __builtin_amdgcn_rcpf(x); }

__device__ __forceinline__ float exp2_(float x) {
#if __has_builtin(__builtin_amdgcn_exp2f)
    return __builtin_amdgcn_exp2f(x);
#else
    return exp2f(x);
#endif
}

__device__ __forceinline__ void sbar() { __builtin_amdgcn_sched_barrier(0); }

// full-wave backward permute: dst = src[lane bidx/4]
__device__ __forceinline__ float bperm(int bidx, float v) {
    return __int_as_float(__builtin_amdgcn_ds_bpermute(bidx, __float_as_int(v)));
}

__device__ __forceinline__ unsigned pkh(float a, float b) {
    auto t = __builtin_amdgcn_cvt_pkrtz(a, b);   // __fp16 ext_vector(2)
    unsigned q; __builtin_memcpy(&q, &t, 4); return q;
}

__device__ __forceinline__ unsigned short f2h(float x) {
    _Float16 h = (_Float16)x;                    // RTE
    unsigned short s; __builtin_memcpy(&s, &h, 2); return s;
}

__device__ __forceinline__ float h2f(unsigned short s) {
    _Float16 h; __builtin_memcpy(&h, &s, 2); return (float)h;
}

// ------- Layer 0: x [S][B][3] f32 -> ws planes [2][S][B] 12B fp16 rows -------
__global__ __launch_bounds__(64) __attribute__((amdgpu_waves_per_eu(1, 2)))
void lstm_layer0(
    const float* __restrict__ x,
    const float* __restrict__ wih_f, const float* __restrict__ whh_f,
    const float* __restrict__ bih_f, const float* __restrict__ bhh_f,
    const float* __restrict__ wih_r, const float* __restrict__ whh_r,
    const float* __restrict__ bih_r, const float* __restrict__ bhh_r,
    unsigned short* __restrict__ ws,
    float* __restrict__ outbase)
{
    const int l64 = threadIdx.x & 63;
    int r = l64 / 5; r = (r > 11) ? 11 : r;     // row-in-wave 0..11
    const int u   = l64 - r * 5;                // 0..4 active (5..8 on idle lanes)
    const int uc  = (u < 5) ? u : 4;
    const int gid = blockIdx.x * 12 + r;
    const bool valid = gid < NROW;
    const int dir = (gid >> 13) & 1;
    const int b   = gid & 8191;
    const bool stw = valid && (u < 3);          // per-lane dword row-store
    const bool st  = valid && (u < 5);          // epilogue-store lanes

    int bidx[5];
#pragma unroll
    for (int k = 0; k < 5; k++) bidx[k] = (r * 5 + k) * 4;

    const float* __restrict__ wih = dir ? wih_r : wih_f;
    const float* __restrict__ whh = dir ? whh_r : whh_f;
    const float* __restrict__ bih = dir ? bih_r : bih_f;
    const float* __restrict__ bhh = dir ? bhh_r : bhh_f;

    // 4 gate rows for unit uc: i,f,g,o = rows uc, 5+uc, 10+uc, 15+uc
    const int rows[4] = {uc, 5 + uc, 10 + uc, 15 + uc};
    const float scl[4] = {-L2E, -L2E, T2E, -L2E};
    float WX[4][3], WH[4][5], BS[4];
#pragma unroll
    for (int gi = 0; gi < 4; gi++) {
        const int rr = rows[gi]; const float sc = scl[gi];
#pragma unroll
        for (int i = 0; i < 3; i++) WX[gi][i] = wih[rr * 3 + i] * sc;
#pragma unroll
        for (int k = 0; k < 5; k++) WH[gi][k] = whh[rr * 5 + k] * sc;
        BS[gi] = (bih[rr] + bhh[rr]) * sc;
    }

    float h[5] = {0.f, 0.f, 0.f, 0.f, 0.f};
    float cp = 0.f, hu_last = 0.f;              // cp = c * 2log2e

    const int t0 = dir ? (S_ - 1) : 0;
    const float* xp = x + ((size_t)t0 * B_ + b) * 3;
    unsigned short* wp = ws + (size_t)dir * ((size_t)S_ * B_ * 6)
                            + ((size_t)t0 * B_ + b) * 6;
    const ptrdiff_t xst = dir ? -(ptrdiff_t)3 * B_ : (ptrdiff_t)3 * B_;
    const ptrdiff_t wst = dir ? -(ptrdiff_t)6 * B_ : (ptrdiff_t)6 * B_;

    auto step = [&](const float (&xin)[3], unsigned short* wpp) {
        float a0 = BS[0], a1 = BS[1], a2 = BS[2], a3 = BS[3];
#pragma unroll
        for (int i = 0; i < 3; i++) {
            a0 = fmaf(WX[0][i], xin[i], a0);
            a1 = fmaf(WX[1][i], xin[i], a1);
            a2 = fmaf(WX[2][i], xin[i], a2);
            a3 = fmaf(WX[3][i], xin[i], a3);
        }
#pragma unroll
        for (int k = 0; k < 5; k++) {
            a0 = fmaf(WH[0][k], h[k], a0);
            a1 = fmaf(WH[1][k], h[k], a1);
            a2 = fmaf(WH[2][k], h[k], a2);
            a3 = fmaf(WH[3][k], h[k], a3);
        }
        const float ig = rcp_(1.0f + exp2_(a0));                       // sigmoid i
        const float fg = rcp_(1.0f + exp2_(a1));                       // sigmoid f
        const float g2 = fmaf(-2.0f * T2E, rcp_(1.0f + exp2_(a2)), T2E); // 2log2e*tanh g
        const float og = rcp_(1.0f + exp2_(a3));                       // sigmoid o
        cp = fmaf(fg, cp, ig * g2);
        const float th = fmaf(-2.0f, rcp_(1.0f + exp2_(cp)), 1.0f);
        const float hu = og * th;
        hu_last = hu;
#pragma unroll
        for (int k = 0; k < 5; k++) h[k] = bperm(bidx[k], hu);
        // pack + per-lane dword store: lane u (<3) writes dword u of the row
        const unsigned q0 = pkh(h[0], h[1]);
        const unsigned q1 = pkh(h[2], h[3]);
        const unsigned q2 = pkh(h[4], 0.0f);
        unsigned qs = q0;
        qs = (u == 1) ? q1 : qs;
        qs = (u == 2) ? q2 : qs;
        if (stw) ((unsigned*)wpp)[u] = qs;
    };

    auto ld = [&](float (&buf)[3]) {
        __builtin_memcpy(&buf[0], xp, 12);
        xp += xst;
        sbar();
    };

    float x0[3], x1[3], x2[3], x3[3], x4[3], x5[3], x6[3], x7[3];
    ld(x0); ld(x1); ld(x2); ld(x3); ld(x4); ld(x5); ld(x6); ld(x7);

#pragma unroll 1
    for (int s = 0; s < S_ - 8; s += 8) {
        step(x0, wp); wp += wst; ld(x0);
        step(x1, wp); wp += wst; ld(x1);
        step(x2, wp); wp += wst; ld(x2);
        step(x3, wp); wp += wst; ld(x3);
        step(x4, wp); wp += wst; ld(x4);
        step(x5, wp); wp += wst; ld(x5);
        step(x6, wp); wp += wst; ld(x6);
        step(x7, wp); wp += wst; ld(x7);
    }
    step(x0, wp); wp += wst;
    step(x1, wp); wp += wst;
    step(x2, wp); wp += wst;
    step(x3, wp); wp += wst;
    step(x4, wp); wp += wst;
    step(x5, wp); wp += wst;
    step(x6, wp); wp += wst;
    step(x7, wp);

    const size_t OUTE = (size_t)S_ * B_ * 10;
    float* hn = outbase + OUTE + ((size_t)dir * B_ + b) * 5;
    float* cn = hn + (size_t)4 * B_ * 5;
    if (st) { hn[uc] = hu_last; cn[uc] = cp * IT2E; }
}

// ------- Layer 1: ws planes -> out [S][B][10] f32, meet-in-the-middle -------
__global__ __launch_bounds__(64) __attribute__((amdgpu_waves_per_eu(1, 2)))
void lstm_layer1(
    const unsigned short* __restrict__ ws,
    const float* __restrict__ wih_f, const float* __restrict__ whh_f,
    const float* __restrict__ bih_f, const float* __restrict__ bhh_f,
    const float* __restrict__ wih_r, const float* __restrict__ whh_r,
    const float* __restrict__ bih_r, const float* __restrict__ bhh_r,
    float* __restrict__ outbase,
    unsigned short* __restrict__ gtemp)
{
    __shared__ unsigned short lt[TL * 60];      // 24960B -> 6 blocks/CU

    const int l64 = threadIdx.x & 63;
    int r = l64 / 5; r = (r > 11) ? 11 : r;     // row-in-wave 0..11
    const int u   = l64 - r * 5;
    const int uc  = (u < 5) ? u : 4;
    const int rm  = (r < 6) ? r : r - 6;        // b-slot 0..5
    const int dir = (r >= 6) ? 1 : 0;           // rows 0-5 fwd, 6-11 bwd
    const int braw = blockIdx.x * 6 + rm;
    const bool valid = braw < B_;
    const int b   = valid ? braw : (B_ - 1);
    const bool st = valid && (u < 5);
    const bool lw = (l64 < 60);                 // LDS-stash lanes
    const int dir5 = dir * 5;
    const int pslot = (dir ? (r - 6) : (r + 6)) * 5 + uc;  // partner slot 0..59

    int bidx[5];
#pragma unroll
    for (int k = 0; k < 5; k++) bidx[k] = (r * 5 + k) * 4;

    const float* __restrict__ wih = dir ? wih_r : wih_f;
    const float* __restrict__ whh = dir ? whh_r : whh_f;
    const float* __restrict__ bih = dir ? bih_r : bih_f;
    const float* __restrict__ bhh = dir ? bhh_r : bhh_f;

    const int rows[4] = {uc, 5 + uc, 10 + uc, 15 + uc};
    const float scl[4] = {-L2E, -L2E, T2E, -L2E};
    // x-weights as fp16 pairs matching the two 12B plane rows:
    // fwd plane pairs p=0..2: (w0,w1)(w2,w3)(w4,0)
    // bwd plane pairs p=3..5: (w5,w6)(w7,w8)(w9,0)
    v2h WX[4][6];
    float WH[4][5], BS[4];
#pragma unroll
    for (int gi = 0; gi < 4; gi++) {
        const int rr = rows[gi]; const float sc = scl[gi];
#pragma unroll
        for (int p = 0; p < 6; p++) {
            const int i0 = (p < 3) ? 2 * p : 2 * p - 1;   // 0,2,4,5,7,9
            const bool pad = (p == 2) || (p == 5);
            const float w0 = wih[rr * 10 + i0] * sc;
            const float w1 = pad ? 0.f : wih[rr * 10 + i0 + 1] * sc;
            WX[gi][p] = (v2h){(_Float16)w0, (_Float16)w1};
        }
#pragma unroll
        for (int k = 0; k < 5; k++) WH[gi][k] = whh[rr * 5 + k] * sc;
        BS[gi] = (bih[rr] + bhh[rr]) * sc;
    }

    float h[5] = {0.f, 0.f, 0.f, 0.f, 0.f};
    float cp = 0.f, hu_last = 0.f;

    const int t0 = dir ? (S_ - 1) : 0;          // this row's s at t=0
    const unsigned short* rpf = ws + ((size_t)t0 * B_ + b) * 6;
    const unsigned short* rpb = rpf + (size_t)S_ * B_ * 6;
    // out pointer starts at the FIRST ROW PHASE 2 WRITES:
    // fwd: s = 256 (t=256); bwd: s = 255 (t=256 -> s=511-256).
    float* op = outbase + ((size_t)(dir ? 255 : 256) * B_ + b) * 10;
    const ptrdiff_t rst = dir ? -(ptrdiff_t)6 * B_ : (ptrdiff_t)6 * B_;
    const ptrdiff_t ost = dir ? -(ptrdiff_t)10 * B_ : (ptrdiff_t)10 * B_;

    // spill pointers (phi1 steps TL..255 -> rows 0..47 of gtemp)
    unsigned short* gw = gtemp + (size_t)blockIdx.x * 64 + l64;
    const unsigned short* gr = gtemp + (size_t)47 * GSTR
                                     + (size_t)blockIdx.x * 64 + pslot;

    // core LSTM step: consumes xin + h, updates cp, returns hu (lane's own h)
    auto core = [&](const v2h (&xin)[6]) -> float {
        float a0 = BS[0], a1 = BS[1], a2 = BS[2], a3 = BS[3];
#pragma unroll
        for (int p = 0; p < 6; p++) {
            a0 = dot2h(xin[p], WX[0][p], a0);
            a1 = dot2h(xin[p], WX[1][p], a1);
            a2 = dot2h(xin[p], WX[2][p], a2);
            a3 = dot2h(xin[p], WX[3][p], a3);
        }
#pragma unroll
        for (int k = 0; k < 5; k++) {
            a0 = fmaf(WH[0][k], h[k], a0);
            a1 = fmaf(WH[1][k], h[k], a1);
            a2 = fmaf(WH[2][k], h[k], a2);
            a3 = fmaf(WH[3][k], h[k], a3);
        }
        const float ig = rcp_(1.0f + exp2_(a0));
        const float fg = rcp_(1.0f + exp2_(a1));
        const float g2 = fmaf(-2.0f * T2E, rcp_(1.0f + exp2_(a2)), T2E);
        const float og = rcp_(1.0f + exp2_(a3));
        cp = fmaf(fg, cp, ig * g2);
        const float th = fmaf(-2.0f, rcp_(1.0f + exp2_(cp)), 1.0f);
        const float hu = og * th;
        hu_last = hu;
        return hu;
    };

    auto bcast = [&](float hu) {
#pragma unroll
        for (int k = 0; k < 5; k++) h[k] = bperm(bidx[k], hu);
    };

    // phi1 step, LDS stash (t < TL)
    auto step1L = [&](const v2h (&xin)[6], int t) {
        const float hu = core(xin);
        if (lw) lt[t * 60 + l64] = f2h(hu);
        bcast(hu);
    };
    // phi1 step, global stash (TL <= t < 256); 128B/wave contiguous
    auto step1G = [&](const v2h (&xin)[6]) {
        const float hu = core(xin);
        *gw = f2h(hu);
        gw += GSTR;
        bcast(hu);
    };
    // phi2 step, partner from global (256 <= t < 304)
    auto step2G = [&](const v2h (&xin)[6], float* opp) {
        const float pv = h2f(*gr);
        gr -= GSTR;
        const float hu = core(xin);
        if (st) { opp[dir5 + u] = hu; opp[5 - dir5 + u] = pv; }
        bcast(hu);
    };
    // phi2 step, partner from LDS (t >= 304)
    auto step2L = [&](const v2h (&xin)[6], int t, float* opp) {
        const float pv = h2f(lt[(511 - t) * 60 + pslot]);
        const float hu = core(xin);
        if (st) { opp[dir5 + u] = hu; opp[5 - dir5 + u] = pv; }
        bcast(hu);
    };

    auto ld = [&](v2h (&buf)[6]) {
        __builtin_memcpy(&buf[0], rpf, 12);
        __builtin_memcpy(&buf[3], rpb, 12);
        rpf += rst; rpb += rst;
        sbar();
    };

    v2h x0[6], x1[6], x2[6], x3[6];
    ld(x0); ld(x1); ld(x2); ld(x3);             // t = 0..3

    // phi1a: t = 0..207 (LDS stash), loads t+4 = 4..211
#pragma unroll 1
    for (int t = 0; t < TL; t += 4) {
        step1L(x0, t + 0); ld(x0);
        step1L(x1, t + 1); ld(x1);
        step1L(x2, t + 2); ld(x2);
        step1L(x3, t + 3); ld(x3);
    }
    // phi1b: t = 208..255 (global stash), loads 212..259
#pragma unroll 1
    for (int t = TL; t < 256; t += 4) {
        step1G(x0); ld(x0);
        step1G(x1); ld(x1);
        step1G(x2); ld(x2);
        step1G(x3); ld(x3);
    }
    // phi2a: t = 256..303 (partner from global), loads 260..307
#pragma unroll 1
    for (int t = 256; t < 304; t += 4) {
        step2G(x0, op); op += ost; ld(x0);
        step2G(x1, op); op += ost; ld(x1);
        step2G(x2, op); op += ost; ld(x2);
        step2G(x3, op); op += ost; ld(x3);
    }
    // phi2b: t = 304..507 (partner from LDS), loads 308..511
#pragma unroll 1
    for (int t = 304; t < 508; t += 4) {
        step2L(x0, t + 0, op); op += ost; ld(x0);
        step2L(x1, t + 1, op); op += ost; ld(x1);
        step2L(x2, t + 2, op); op += ost; ld(x2);
        step2L(x3, t + 3, op); op += ost; ld(x3);
    }
    // tail: t = 508..511, no more loads
    step2L(x0, 508, op); op += ost;
    step2L(x1, 509, op); op += ost;
    step2L(x2, 510, op); op += ost;
    step2L(x3, 511, op);

    const size_t OUTE = (size_t)S_ * B_ * 10;
    float* hn = outbase + OUTE + ((size_t)(2 + dir) * B_ + b) * 5;
    float* cn = hn + (size_t)4 * B_ * 5;
    if (st) { hn[uc] = hu_last; cn[uc] = cp * IT2E; }
}

extern "C" void kernel_launch(void* const* d_in, const int* in_sizes, int n_in,
                              void* d_out, int out_size, void* d_ws, size_t ws_size,
                              hipStream_t stream) {
    const float* x       = (const float*)d_in[0];
    const float* wih_l0  = (const float*)d_in[1];
    const float* whh_l0  = (const float*)d_in[2];
    const float* bih_l0  = (const float*)d_in[3];
    const float* bhh_l0  = (const float*)d_in[4];
    const float* wih_l0r = (const float*)d_in[5];
    const float* whh_l0r = (const float*)d_in[6];
    const float* bih_l0r = (const float*)d_in[7];
    const float* bhh_l0r = (const float*)d_in[8];
    const float* wih_l1  = (const float*)d_in[9];
    const float* whh_l1  = (const float*)d_in[10];
    const float* bih_l1  = (const float*)d_in[11];
    const float* bhh_l1  = (const float*)d_in[12];
    const float* wih_l1r = (const float*)d_in[13];
    const float* whh_l1r = (const float*)d_in[14];
    const float* bih_l1r = (const float*)d_in[15];
    const float* bhh_l1r = (const float*)d_in[16];

    float* out = (float*)d_out;
    unsigned short* ws = (unsigned short*)d_ws;   // 2 planes * S*B*12B = 100.7 MB
    // phi1 spill: 48 steps * 1366 waves * 64 shorts = 8.4 MB, after ws planes
    unsigned short* gtemp = ws + (size_t)2 * S_ * B_ * 6;

    // layer0: 16384 (dir,row) sequences, 12 per wave -> 1366 single-wave blocks
    dim3 grid0(1366), block(64);
    lstm_layer0<<<grid0, block, 0, stream>>>(x,
        wih_l0, whh_l0, bih_l0, bhh_l0,
        wih_l0r, whh_l0r, bih_l0r, bhh_l0r,
        ws, out);
    // layer1: 6 b-values x 2 dirs per wave -> ceil(8192/6) = 1366 blocks
    dim3 grid1(GD1);
    lstm_layer1<<<grid1, block, 0, stream>>>(ws,
        wih_l1, whh_l1, bih_l1, bhh_l1,
        wih_l1r, whh_l1r, bih_l1r, bhh_l1r,
        out, gtemp);
}

// Round 4
// 327.543 us; speedup vs baseline: 1.0100x; 1.0100x over previous
//
#include <hip/hip_runtime.h>

// Two-layer bidirectional LSTM, S=512, B=8192, I=3, H=5.
// R20: layer1 occupancy attack. R19 proved stores are not the pacer
// (WRITE halved, dur flat); layer1 is latency-bound at 1.33 waves/SIMD
// (occupancy 12%, VALUBusy 46%). Restructure layer1 to 8 rows/wave in
// 8-LANE groups (4 b x 2 dirs, lanes u=0..4 active): grid 1366 -> 2048
// = exactly 2 waves/SIMD, 8 blocks/CU. MITM retuned: TL=240 steps in
// LDS (19200B -> LDS-fits 8 blocks/CU), 16-step global spill with
// 4-deep register prefetch of partner values + one-time vmcnt(0) at
// the phase boundary (same-wave spill write->read gap is now 1 step).
// Layer0 unchanged (12 rows/wave, ~issue-bound already).
// Carried: unit-per-lane, fp16 ws planes, fdot2 x-dots, depth-4/8
// rotating prefetch, sched_barrier after loads, full-sector out runs.

constexpr int S_ = 512;
constexpr int B_ = 8192;
constexpr int NROW = 16384;    // 2 dirs * 8192

constexpr int GD1  = 2048;         // layer1 grid = 8192 / 4
constexpr int TL   = 240;          // phi1 steps resident in LDS
constexpr int GSTR = GD1 * 64;     // spill stride per step (shorts)

constexpr float L2E  = 1.4426950408889634f;   // log2(e)
constexpr float T2E  = 2.8853900817779268f;   // 2*log2(e)
constexpr float IT2E = 0.34657359027997264f;  // 1/(2*log2(e))

typedef _Float16 v2h __attribute__((ext_vector_type(2)));

__device__ __forceinline__ float dot2h(v2h a, v2h b, float c) {
#if __has_builtin(__builtin_amdgcn_fdot2)
    return __builtin_amdgcn_fdot2(a, b, c, false);
#else
    return fmaf((float)a[0], (float)b[0], fmaf((float)a[1], (float)b[1], c));
#endif
}

__device__ __forceinline__ float rcp_(float x) { return __builtin_amdgcn_rcpf(x); }

__device__ __forceinline__ float exp2_(float x) {
#if __has_builtin(__builtin_amdgcn_exp2f)
    return __builtin_amdgcn_exp2f(x);
#else
    return exp2f(x);
#endif
}

__device__ __forceinline__ void sbar() { __builtin_amdgcn_sched_barrier(0); }

// full-wave backward permute: dst = src[lane bidx/4]
__device__ __forceinline__ float bperm(int bidx, float v) {
    return __int_as_float(__builtin_amdgcn_ds_bpermute(bidx, __float_as_int(v)));
}

__device__ __forceinline__ unsigned pkh(float a, float b) {
    auto t = __builtin_amdgcn_cvt_pkrtz(a, b);   // __fp16 ext_vector(2)
    unsigned q; __builtin_memcpy(&q, &t, 4); return q;
}

__device__ __forceinline__ unsigned short f2h(float x) {
    _Float16 h = (_Float16)x;                    // RTE
    unsigned short s; __builtin_memcpy(&s, &h, 2); return s;
}

__device__ __forceinline__ float h2f(unsigned short s) {
    _Float16 h; __builtin_memcpy(&h, &s, 2); return (float)h;
}

// ------- Layer 0: x [S][B][3] f32 -> ws planes [2][S][B] 12B fp16 rows -------
__global__ __launch_bounds__(64) __attribute__((amdgpu_waves_per_eu(1, 2)))
void lstm_layer0(
    const float* __restrict__ x,
    const float* __restrict__ wih_f, const float* __restrict__ whh_f,
    const float* __restrict__ bih_f, const float* __restrict__ bhh_f,
    const float* __restrict__ wih_r, const float* __restrict__ whh_r,
    const float* __restrict__ bih_r, const float* __restrict__ bhh_r,
    unsigned short* __restrict__ ws,
    float* __restrict__ outbase)
{
    const int l64 = threadIdx.x & 63;
    int r = l64 / 5; r = (r > 11) ? 11 : r;     // row-in-wave 0..11
    const int u   = l64 - r * 5;                // 0..4 active (5..8 on idle lanes)
    const int uc  = (u < 5) ? u : 4;
    const int gid = blockIdx.x * 12 + r;
    const bool valid = gid < NROW;
    const int dir = (gid >> 13) & 1;
    const int b   = gid & 8191;
    const bool stw = valid && (u < 3);          // per-lane dword row-store
    const bool st  = valid && (u < 5);          // epilogue-store lanes

    int bidx[5];
#pragma unroll
    for (int k = 0; k < 5; k++) bidx[k] = (r * 5 + k) * 4;

    const float* __restrict__ wih = dir ? wih_r : wih_f;
    const float* __restrict__ whh = dir ? whh_r : whh_f;
    const float* __restrict__ bih = dir ? bih_r : bih_f;
    const float* __restrict__ bhh = dir ? bhh_r : bhh_f;

    // 4 gate rows for unit uc: i,f,g,o = rows uc, 5+uc, 10+uc, 15+uc
    const int rows[4] = {uc, 5 + uc, 10 + uc, 15 + uc};
    const float scl[4] = {-L2E, -L2E, T2E, -L2E};
    float WX[4][3], WH[4][5], BS[4];
#pragma unroll
    for (int gi = 0; gi < 4; gi++) {
        const int rr = rows[gi]; const float sc = scl[gi];
#pragma unroll
        for (int i = 0; i < 3; i++) WX[gi][i] = wih[rr * 3 + i] * sc;
#pragma unroll
        for (int k = 0; k < 5; k++) WH[gi][k] = whh[rr * 5 + k] * sc;
        BS[gi] = (bih[rr] + bhh[rr]) * sc;
    }

    float h[5] = {0.f, 0.f, 0.f, 0.f, 0.f};
    float cp = 0.f, hu_last = 0.f;              // cp = c * 2log2e

    const int t0 = dir ? (S_ - 1) : 0;
    const float* xp = x + ((size_t)t0 * B_ + b) * 3;
    unsigned short* wp = ws + (size_t)dir * ((size_t)S_ * B_ * 6)
                            + ((size_t)t0 * B_ + b) * 6;
    const ptrdiff_t xst = dir ? -(ptrdiff_t)3 * B_ : (ptrdiff_t)3 * B_;
    const ptrdiff_t wst = dir ? -(ptrdiff_t)6 * B_ : (ptrdiff_t)6 * B_;

    auto step = [&](const float (&xin)[3], unsigned short* wpp) {
        float a0 = BS[0], a1 = BS[1], a2 = BS[2], a3 = BS[3];
#pragma unroll
        for (int i = 0; i < 3; i++) {
            a0 = fmaf(WX[0][i], xin[i], a0);
            a1 = fmaf(WX[1][i], xin[i], a1);
            a2 = fmaf(WX[2][i], xin[i], a2);
            a3 = fmaf(WX[3][i], xin[i], a3);
        }
#pragma unroll
        for (int k = 0; k < 5; k++) {
            a0 = fmaf(WH[0][k], h[k], a0);
            a1 = fmaf(WH[1][k], h[k], a1);
            a2 = fmaf(WH[2][k], h[k], a2);
            a3 = fmaf(WH[3][k], h[k], a3);
        }
        const float ig = rcp_(1.0f + exp2_(a0));                       // sigmoid i
        const float fg = rcp_(1.0f + exp2_(a1));                       // sigmoid f
        const float g2 = fmaf(-2.0f * T2E, rcp_(1.0f + exp2_(a2)), T2E); // 2log2e*tanh g
        const float og = rcp_(1.0f + exp2_(a3));                       // sigmoid o
        cp = fmaf(fg, cp, ig * g2);
        const float th = fmaf(-2.0f, rcp_(1.0f + exp2_(cp)), 1.0f);
        const float hu = og * th;
        hu_last = hu;
#pragma unroll
        for (int k = 0; k < 5; k++) h[k] = bperm(bidx[k], hu);
        // pack + per-lane dword store: lane u (<3) writes dword u of the row
        const unsigned q0 = pkh(h[0], h[1]);
        const unsigned q1 = pkh(h[2], h[3]);
        const unsigned q2 = pkh(h[4], 0.0f);
        unsigned qs = q0;
        qs = (u == 1) ? q1 : qs;
        qs = (u == 2) ? q2 : qs;
        if (stw) ((unsigned*)wpp)[u] = qs;
    };

    auto ld = [&](float (&buf)[3]) {
        __builtin_memcpy(&buf[0], xp, 12);
        xp += xst;
        sbar();
    };

    float x0[3], x1[3], x2[3], x3[3], x4[3], x5[3], x6[3], x7[3];
    ld(x0); ld(x1); ld(x2); ld(x3); ld(x4); ld(x5); ld(x6); ld(x7);

#pragma unroll 1
    for (int s = 0; s < S_ - 8; s += 8) {
        step(x0, wp); wp += wst; ld(x0);
        step(x1, wp); wp += wst; ld(x1);
        step(x2, wp); wp += wst; ld(x2);
        step(x3, wp); wp += wst; ld(x3);
        step(x4, wp); wp += wst; ld(x4);
        step(x5, wp); wp += wst; ld(x5);
        step(x6, wp); wp += wst; ld(x6);
        step(x7, wp); wp += wst; ld(x7);
    }
    step(x0, wp); wp += wst;
    step(x1, wp); wp += wst;
    step(x2, wp); wp += wst;
    step(x3, wp); wp += wst;
    step(x4, wp); wp += wst;
    step(x5, wp); wp += wst;
    step(x6, wp); wp += wst;
    step(x7, wp);

    const size_t OUTE = (size_t)S_ * B_ * 10;
    float* hn = outbase + OUTE + ((size_t)dir * B_ + b) * 5;
    float* cn = hn + (size_t)4 * B_ * 5;
    if (st) { hn[uc] = hu_last; cn[uc] = cp * IT2E; }
}

// ------- Layer 1: ws planes -> out [S][B][10] f32, MITM, 8-lane groups -------
__global__ __launch_bounds__(64) __attribute__((amdgpu_waves_per_eu(2, 4)))
void lstm_layer1(
    const unsigned short* __restrict__ ws,
    const float* __restrict__ wih_f, const float* __restrict__ whh_f,
    const float* __restrict__ bih_f, const float* __restrict__ bhh_f,
    const float* __restrict__ wih_r, const float* __restrict__ whh_r,
    const float* __restrict__ bih_r, const float* __restrict__ bhh_r,
    float* __restrict__ outbase,
    unsigned short* __restrict__ gtemp)
{
    __shared__ unsigned short lt[TL * 40];      // 19200B -> 8 blocks/CU

    const int l64 = threadIdx.x & 63;
    const int r  = l64 >> 3;                    // row 0..7
    const int u  = l64 & 7;                     // 0..7, active u<5
    const int uc = (u < 5) ? u : 4;
    const int rm  = r & 3;                      // b-slot 0..3
    const int dir = r >> 2;                     // rows 0-3 fwd, 4-7 bwd
    const int b   = blockIdx.x * 4 + rm;        // 4*2048 = 8192 exact, no tail
    const bool st = (u < 5);
    const int dir5 = dir * 5;
    const int pr  = dir ? (r - 4) : (r + 4);    // partner row in wave
    const int psL = pr * 5 + uc;                // compact LDS partner slot
    const int psG = pr * 8 + uc;                // lane-indexed spill partner slot

    int bidx[5];
#pragma unroll
    for (int k = 0; k < 5; k++) bidx[k] = (r * 8 + k) * 4;

    const float* __restrict__ wih = dir ? wih_r : wih_f;
    const float* __restrict__ whh = dir ? whh_r : whh_f;
    const float* __restrict__ bih = dir ? bih_r : bih_f;
    const float* __restrict__ bhh = dir ? bhh_r : bhh_f;

    const int rows[4] = {uc, 5 + uc, 10 + uc, 15 + uc};
    const float scl[4] = {-L2E, -L2E, T2E, -L2E};
    // x-weights as fp16 pairs matching the two 12B plane rows:
    // fwd plane pairs p=0..2: (w0,w1)(w2,w3)(w4,0)
    // bwd plane pairs p=3..5: (w5,w6)(w7,w8)(w9,0)
    v2h WX[4][6];
    float WH[4][5], BS[4];
#pragma unroll
    for (int gi = 0; gi < 4; gi++) {
        const int rr = rows[gi]; const float sc = scl[gi];
#pragma unroll
        for (int p = 0; p < 6; p++) {
            const int i0 = (p < 3) ? 2 * p : 2 * p - 1;   // 0,2,4,5,7,9
            const bool pad = (p == 2) || (p == 5);
            const float w0 = wih[rr * 10 + i0] * sc;
            const float w1 = pad ? 0.f : wih[rr * 10 + i0 + 1] * sc;
            WX[gi][p] = (v2h){(_Float16)w0, (_Float16)w1};
        }
#pragma unroll
        for (int k = 0; k < 5; k++) WH[gi][k] = whh[rr * 5 + k] * sc;
        BS[gi] = (bih[rr] + bhh[rr]) * sc;
    }

    float h[5] = {0.f, 0.f, 0.f, 0.f, 0.f};
    float cp = 0.f, hu_last = 0.f;

    const int t0 = dir ? (S_ - 1) : 0;          // this row's s at t=0
    const unsigned short* rpf = ws + ((size_t)t0 * B_ + b) * 6;
    const unsigned short* rpb = rpf + (size_t)S_ * B_ * 6;
    // out pointer starts at the first row phase 2 writes:
    // fwd: s = 256 (t=256); bwd: s = 255 (t=256 -> s=511-256).
    float* op = outbase + ((size_t)(dir ? 255 : 256) * B_ + b) * 10;
    const ptrdiff_t rst = dir ? -(ptrdiff_t)6 * B_ : (ptrdiff_t)6 * B_;
    const ptrdiff_t ost = dir ? -(ptrdiff_t)10 * B_ : (ptrdiff_t)10 * B_;

    // spill (phi1 steps 240..255 -> rows 0..15 of gtemp; 4 guard rows below)
    unsigned short* gw = gtemp + (size_t)blockIdx.x * 64 + l64;
    const unsigned short* gr = gtemp + (size_t)15 * GSTR
                                     + (size_t)blockIdx.x * 64 + psG;

    // core LSTM step: consumes xin + h, updates cp, returns hu (lane's own h)
    auto core = [&](const v2h (&xin)[6]) -> float {
        float a0 = BS[0], a1 = BS[1], a2 = BS[2], a3 = BS[3];
#pragma unroll
        for (int p = 0; p < 6; p++) {
            a0 = dot2h(xin[p], WX[0][p], a0);
            a1 = dot2h(xin[p], WX[1][p], a1);
            a2 = dot2h(xin[p], WX[2][p], a2);
            a3 = dot2h(xin[p], WX[3][p], a3);
        }
#pragma unroll
        for (int k = 0; k < 5; k++) {
            a0 = fmaf(WH[0][k], h[k], a0);
            a1 = fmaf(WH[1][k], h[k], a1);
            a2 = fmaf(WH[2][k], h[k], a2);
            a3 = fmaf(WH[3][k], h[k], a3);
        }
        const float ig = rcp_(1.0f + exp2_(a0));
        const float fg = rcp_(1.0f + exp2_(a1));
        const float g2 = fmaf(-2.0f * T2E, rcp_(1.0f + exp2_(a2)), T2E);
        const float og = rcp_(1.0f + exp2_(a3));
        cp = fmaf(fg, cp, ig * g2);
        const float th = fmaf(-2.0f, rcp_(1.0f + exp2_(cp)), 1.0f);
        const float hu = og * th;
        hu_last = hu;
        return hu;
    };

    auto bcast = [&](float hu) {
#pragma unroll
        for (int k = 0; k < 5; k++) h[k] = bperm(bidx[k], hu);
    };

    // phi1 step, LDS stash (t < TL)
    auto step1L = [&](const v2h (&xin)[6], int t) {
        const float hu = core(xin);
        if (st) lt[t * 40 + r * 5 + u] = f2h(hu);
        bcast(hu);
    };
    // phi1 step, global stash (TL <= t < 256); 128B/wave contiguous
    auto step1G = [&](const v2h (&xin)[6]) {
        const float hu = core(xin);
        *gw = f2h(hu);
        gw += GSTR;
        bcast(hu);
    };
    // phi2 step, partner pre-loaded from global (256 <= t < 272)
    auto step2G = [&](const v2h (&xin)[6], unsigned short pvs, float* opp) {
        const float pv = h2f(pvs);
        const float hu = core(xin);
        if (st) { opp[dir5 + u] = hu; opp[5 - dir5 + u] = pv; }
        bcast(hu);
    };
    // phi2 step, partner from LDS (t >= 272)
    auto step2L = [&](const v2h (&xin)[6], int t, float* opp) {
        const float pv = h2f(lt[(511 - t) * 40 + psL]);
        const float hu = core(xin);
        if (st) { opp[dir5 + u] = hu; opp[5 - dir5 + u] = pv; }
        bcast(hu);
    };

    auto ld = [&](v2h (&buf)[6]) {
        __builtin_memcpy(&buf[0], rpf, 12);
        __builtin_memcpy(&buf[3], rpb, 12);
        rpf += rst; rpb += rst;
        sbar();
    };

    v2h x0[6], x1[6], x2[6], x3[6];
    ld(x0); ld(x1); ld(x2); ld(x3);             // t = 0..3

    // phi1a: t = 0..239 (LDS stash), loads 4..243
#pragma unroll 1
    for (int t = 0; t < TL; t += 4) {
        step1L(x0, t + 0); ld(x0);
        step1L(x1, t + 1); ld(x1);
        step1L(x2, t + 2); ld(x2);
        step1L(x3, t + 3); ld(x3);
    }
    // phi1b: t = 240..255 (global stash), loads 244..259
#pragma unroll 1
    for (int t = TL; t < 256; t += 4) {
        step1G(x0); ld(x0);
        step1G(x1); ld(x1);
        step1G(x2); ld(x2);
        step1G(x3); ld(x3);
    }
    // drain: spill row 15 (written t=255) is read at t=256 by this same
    // wave -- vmcnt(0) makes the store L2-visible before the load.
    asm volatile("s_waitcnt vmcnt(0)" ::: "memory");
    // partner prefetch, depth 4 (rows 15..12)
    unsigned short pva = *gr; gr -= GSTR;
    unsigned short pvb = *gr; gr -= GSTR;
    unsigned short pvc = *gr; gr -= GSTR;
    unsigned short pvd = *gr; gr -= GSTR;
    // phi2a: t = 256..271 (partner from spill), loads 260..275;
    // trailing gr reads run into the 4 guard rows below row 0 (unused).
#pragma unroll 1
    for (int t = 256; t < 272; t += 4) {
        step2G(x0, pva, op); op += ost; pva = *gr; gr -= GSTR; ld(x0);
        step2G(x1, pvb, op); op += ost; pvb = *gr; gr -= GSTR; ld(x1);
        step2G(x2, pvc, op); op += ost; pvc = *gr; gr -= GSTR; ld(x2);
        step2G(x3, pvd, op); op += ost; pvd = *gr; gr -= GSTR; ld(x3);
    }
    // phi2b: t = 272..507 (partner from LDS), loads 276..511
#pragma unroll 1
    for (int t = 272; t < 508; t += 4) {
        step2L(x0, t + 0, op); op += ost; ld(x0);
        step2L(x1, t + 1, op); op += ost; ld(x1);
        step2L(x2, t + 2, op); op += ost; ld(x2);
        step2L(x3, t + 3, op); op += ost; ld(x3);
    }
    // tail: t = 508..511, no more loads
    step2L(x0, 508, op); op += ost;
    step2L(x1, 509, op); op += ost;
    step2L(x2, 510, op); op += ost;
    step2L(x3, 511, op);

    const size_t OUTE = (size_t)S_ * B_ * 10;
    float* hn = outbase + OUTE + ((size_t)(2 + dir) * B_ + b) * 5;
    float* cn = hn + (size_t)4 * B_ * 5;
    if (st) { hn[u] = hu_last; cn[u] = cp * IT2E; }
}

extern "C" void kernel_launch(void* const* d_in, const int* in_sizes, int n_in,
                              void* d_out, int out_size, void* d_ws, size_t ws_size,
                              hipStream_t stream) {
    const float* x       = (const float*)d_in[0];
    const float* wih_l0  = (const float*)d_in[1];
    const float* whh_l0  = (const float*)d_in[2];
    const float* bih_l0  = (const float*)d_in[3];
    const float* bhh_l0  = (const float*)d_in[4];
    const float* wih_l0r = (const float*)d_in[5];
    const float* whh_l0r = (const float*)d_in[6];
    const float* bih_l0r = (const float*)d_in[7];
    const float* bhh_l0r = (const float*)d_in[8];
    const float* wih_l1  = (const float*)d_in[9];
    const float* whh_l1  = (const float*)d_in[10];
    const float* bih_l1  = (const float*)d_in[11];
    const float* bhh_l1  = (const float*)d_in[12];
    const float* wih_l1r = (const float*)d_in[13];
    const float* whh_l1r = (const float*)d_in[14];
    const float* bih_l1r = (const float*)d_in[15];
    const float* bhh_l1r = (const float*)d_in[16];

    float* out = (float*)d_out;
    unsigned short* ws = (unsigned short*)d_ws;   // 2 planes * S*B*12B = 100.7 MB
    // phi1 spill: 4 guard rows + 16 data rows, each 2048*64 shorts (5.2 MB)
    unsigned short* gtemp = ws + (size_t)2 * S_ * B_ * 6 + (size_t)4 * GSTR;

    // layer0: 16384 (dir,row) sequences, 12 per wave -> 1366 single-wave blocks
    dim3 grid0(1366), block(64);
    lstm_layer0<<<grid0, block, 0, stream>>>(x,
        wih_l0, whh_l0, bih_l0, bhh_l0,
        wih_l0r, whh_l0r, bih_l0r, bhh_l0r,
        ws, out);
    // layer1: 4 b-values x 2 dirs per wave -> 2048 blocks = 2 waves/SIMD
    dim3 grid1(GD1);
    lstm_layer1<<<grid1, block, 0, stream>>>(ws,
        wih_l1, whh_l1, bih_l1, bhh_l1,
        wih_l1r, whh_l1r, bih_l1r, bhh_l1r,
        out, gtemp);
}

// Round 5
// 308.896 us; speedup vs baseline: 1.0709x; 1.0604x over previous
//
#include <hip/hip_runtime.h>

// Two-layer bidirectional LSTM, S=512, B=8192, I=3, H=5.
// R21: layer1 memory-latency attack (layer0 untouched from R20).
//  - XCD-aware block swizzle (bsw=(bid&7)*256+bid/8): adjacent-b blocks
//    share 128B ws lines on the SAME XCD L2 -> kills the 2.9x read
//    over-fetch (320MB vs 110MB logical) and HBM-latency x-loads.
//  - depth-8 x prefetch (was 4) + dots->ld->finish step split: x-dots
//    issue before the broadcast lgkmcnt wait; loads precede stores in
//    the in-order vmcnt queue.
//  - phi2a spill partners: all 16 loaded upfront after one vmcnt(0).
//  - ds_swizzle broadcast (and=0x18,or=k) replaces ds_bpermute.
// Structure carried from R20: 8 rows/wave in 8-lane groups (4b x 2dir),
// grid 2048 = 2 waves/SIMD, MITM with TL=240 LDS stash + 16-step spill,
// full-sector out runs, fp16 ws planes, fdot2 x-dots.

constexpr int S_ = 512;
constexpr int B_ = 8192;
constexpr int NROW = 16384;    // 2 dirs * 8192

constexpr int GD1  = 2048;         // layer1 grid = 8192 / 4
constexpr int TL   = 240;          // phi1 steps resident in LDS
constexpr int GSTR = GD1 * 64;     // spill stride per step (shorts)

constexpr float L2E  = 1.4426950408889634f;   // log2(e)
constexpr float T2E  = 2.8853900817779268f;   // 2*log2(e)
constexpr float IT2E = 0.34657359027997264f;  // 1/(2*log2(e))

typedef _Float16 v2h __attribute__((ext_vector_type(2)));

__device__ __forceinline__ float dot2h(v2h a, v2h b, float c) {
#if __has_builtin(__builtin_amdgcn_fdot2)
    return __builtin_amdgcn_fdot2(a, b, c, false);
#else
    return fmaf((float)a[0], (float)b[0], fmaf((float)a[1], (float)b[1], c));
#endif
}

__device__ __forceinline__ float rcp_(float x) { return __builtin_amdgcn_rcpf(x); }

__device__ __forceinline__ float exp2_(float x) {
#if __has_builtin(__builtin_amdgcn_exp2f)
    return __builtin_amdgcn_exp2f(x);
#else
    return exp2f(x);
#endif
}

__device__ __forceinline__ void sbar() { __builtin_amdgcn_sched_barrier(0); }

// full-wave backward permute: dst = src[lane bidx/4]
__device__ __forceinline__ float bperm(int bidx, float v) {
    return __int_as_float(__builtin_amdgcn_ds_bpermute(bidx, __float_as_int(v)));
}

__device__ __forceinline__ unsigned pkh(float a, float b) {
    auto t = __builtin_amdgcn_cvt_pkrtz(a, b);   // __fp16 ext_vector(2)
    unsigned q; __builtin_memcpy(&q, &t, 4); return q;
}

__device__ __forceinline__ unsigned short f2h(float x) {
    _Float16 h = (_Float16)x;                    // RTE
    unsigned short s; __builtin_memcpy(&s, &h, 2); return s;
}

__device__ __forceinline__ float h2f(unsigned short s) {
    _Float16 h; __builtin_memcpy(&h, &s, 2); return (float)h;
}

// ------- Layer 0: x [S][B][3] f32 -> ws planes [2][S][B] 12B fp16 rows -------
__global__ __launch_bounds__(64) __attribute__((amdgpu_waves_per_eu(1, 2)))
void lstm_layer0(
    const float* __restrict__ x,
    const float* __restrict__ wih_f, const float* __restrict__ whh_f,
    const float* __restrict__ bih_f, const float* __restrict__ bhh_f,
    const float* __restrict__ wih_r, const float* __restrict__ whh_r,
    const float* __restrict__ bih_r, const float* __restrict__ bhh_r,
    unsigned short* __restrict__ ws,
    float* __restrict__ outbase)
{
    const int l64 = threadIdx.x & 63;
    int r = l64 / 5; r = (r > 11) ? 11 : r;     // row-in-wave 0..11
    const int u   = l64 - r * 5;                // 0..4 active (5..8 on idle lanes)
    const int uc  = (u < 5) ? u : 4;
    const int gid = blockIdx.x * 12 + r;
    const bool valid = gid < NROW;
    const int dir = (gid >> 13) & 1;
    const int b   = gid & 8191;
    const bool stw = valid && (u < 3);          // per-lane dword row-store
    const bool st  = valid && (u < 5);          // epilogue-store lanes

    int bidx[5];
#pragma unroll
    for (int k = 0; k < 5; k++) bidx[k] = (r * 5 + k) * 4;

    const float* __restrict__ wih = dir ? wih_r : wih_f;
    const float* __restrict__ whh = dir ? whh_r : whh_f;
    const float* __restrict__ bih = dir ? bih_r : bih_f;
    const float* __restrict__ bhh = dir ? bhh_r : bhh_f;

    // 4 gate rows for unit uc: i,f,g,o = rows uc, 5+uc, 10+uc, 15+uc
    const int rows[4] = {uc, 5 + uc, 10 + uc, 15 + uc};
    const float scl[4] = {-L2E, -L2E, T2E, -L2E};
    float WX[4][3], WH[4][5], BS[4];
#pragma unroll
    for (int gi = 0; gi < 4; gi++) {
        const int rr = rows[gi]; const float sc = scl[gi];
#pragma unroll
        for (int i = 0; i < 3; i++) WX[gi][i] = wih[rr * 3 + i] * sc;
#pragma unroll
        for (int k = 0; k < 5; k++) WH[gi][k] = whh[rr * 5 + k] * sc;
        BS[gi] = (bih[rr] + bhh[rr]) * sc;
    }

    float h[5] = {0.f, 0.f, 0.f, 0.f, 0.f};
    float cp = 0.f, hu_last = 0.f;              // cp = c * 2log2e

    const int t0 = dir ? (S_ - 1) : 0;
    const float* xp = x + ((size_t)t0 * B_ + b) * 3;
    unsigned short* wp = ws + (size_t)dir * ((size_t)S_ * B_ * 6)
                            + ((size_t)t0 * B_ + b) * 6;
    const ptrdiff_t xst = dir ? -(ptrdiff_t)3 * B_ : (ptrdiff_t)3 * B_;
    const ptrdiff_t wst = dir ? -(ptrdiff_t)6 * B_ : (ptrdiff_t)6 * B_;

    auto step = [&](const float (&xin)[3], unsigned short* wpp) {
        float a0 = BS[0], a1 = BS[1], a2 = BS[2], a3 = BS[3];
#pragma unroll
        for (int i = 0; i < 3; i++) {
            a0 = fmaf(WX[0][i], xin[i], a0);
            a1 = fmaf(WX[1][i], xin[i], a1);
            a2 = fmaf(WX[2][i], xin[i], a2);
            a3 = fmaf(WX[3][i], xin[i], a3);
        }
#pragma unroll
        for (int k = 0; k < 5; k++) {
            a0 = fmaf(WH[0][k], h[k], a0);
            a1 = fmaf(WH[1][k], h[k], a1);
            a2 = fmaf(WH[2][k], h[k], a2);
            a3 = fmaf(WH[3][k], h[k], a3);
        }
        const float ig = rcp_(1.0f + exp2_(a0));                       // sigmoid i
        const float fg = rcp_(1.0f + exp2_(a1));                       // sigmoid f
        const float g2 = fmaf(-2.0f * T2E, rcp_(1.0f + exp2_(a2)), T2E); // 2log2e*tanh g
        const float og = rcp_(1.0f + exp2_(a3));                       // sigmoid o
        cp = fmaf(fg, cp, ig * g2);
        const float th = fmaf(-2.0f, rcp_(1.0f + exp2_(cp)), 1.0f);
        const float hu = og * th;
        hu_last = hu;
#pragma unroll
        for (int k = 0; k < 5; k++) h[k] = bperm(bidx[k], hu);
        // pack + per-lane dword store: lane u (<3) writes dword u of the row
        const unsigned q0 = pkh(h[0], h[1]);
        const unsigned q1 = pkh(h[2], h[3]);
        const unsigned q2 = pkh(h[4], 0.0f);
        unsigned qs = q0;
        qs = (u == 1) ? q1 : qs;
        qs = (u == 2) ? q2 : qs;
        if (stw) ((unsigned*)wpp)[u] = qs;
    };

    auto ld = [&](float (&buf)[3]) {
        __builtin_memcpy(&buf[0], xp, 12);
        xp += xst;
        sbar();
    };

    float x0[3], x1[3], x2[3], x3[3], x4[3], x5[3], x6[3], x7[3];
    ld(x0); ld(x1); ld(x2); ld(x3); ld(x4); ld(x5); ld(x6); ld(x7);

#pragma unroll 1
    for (int s = 0; s < S_ - 8; s += 8) {
        step(x0, wp); wp += wst; ld(x0);
        step(x1, wp); wp += wst; ld(x1);
        step(x2, wp); wp += wst; ld(x2);
        step(x3, wp); wp += wst; ld(x3);
        step(x4, wp); wp += wst; ld(x4);
        step(x5, wp); wp += wst; ld(x5);
        step(x6, wp); wp += wst; ld(x6);
        step(x7, wp); wp += wst; ld(x7);
    }
    step(x0, wp); wp += wst;
    step(x1, wp); wp += wst;
    step(x2, wp); wp += wst;
    step(x3, wp); wp += wst;
    step(x4, wp); wp += wst;
    step(x5, wp); wp += wst;
    step(x6, wp); wp += wst;
    step(x7, wp);

    const size_t OUTE = (size_t)S_ * B_ * 10;
    float* hn = outbase + OUTE + ((size_t)dir * B_ + b) * 5;
    float* cn = hn + (size_t)4 * B_ * 5;
    if (st) { hn[uc] = hu_last; cn[uc] = cp * IT2E; }
}

// ------- Layer 1: ws planes -> out [S][B][10] f32, MITM, 8-lane groups -------
__global__ __launch_bounds__(64) __attribute__((amdgpu_waves_per_eu(2, 4)))
void lstm_layer1(
    const unsigned short* __restrict__ ws,
    const float* __restrict__ wih_f, const float* __restrict__ whh_f,
    const float* __restrict__ bih_f, const float* __restrict__ bhh_f,
    const float* __restrict__ wih_r, const float* __restrict__ whh_r,
    const float* __restrict__ bih_r, const float* __restrict__ bhh_r,
    float* __restrict__ outbase,
    unsigned short* __restrict__ gtemp)
{
    __shared__ unsigned short lt[TL * 40];      // 19200B -> 8 blocks/CU

    const int l64 = threadIdx.x & 63;
    const int bid = (int)blockIdx.x;
    // XCD swizzle: XCD j (bids === j mod 8) covers a contiguous b range.
    const int bsw = (bid & 7) * 256 + (bid >> 3);
    const int r  = l64 >> 3;                    // row 0..7
    const int u  = l64 & 7;                     // 0..7, active u<5
    const int uc = (u < 5) ? u : 4;
    const int rm  = r & 3;                      // b-slot 0..3
    const int dir = r >> 2;                     // rows 0-3 fwd, 4-7 bwd
    const int b   = bsw * 4 + rm;               // 4*2048 = 8192 exact
    const bool st = (u < 5);
    const int dir5 = dir * 5;
    const int pr  = dir ? (r - 4) : (r + 4);    // partner row in wave
    const int psL = pr * 5 + uc;                // compact LDS partner slot
    const int psG = pr * 8 + uc;                // lane-indexed spill partner slot

    const float* __restrict__ wih = dir ? wih_r : wih_f;
    const float* __restrict__ whh = dir ? whh_r : whh_f;
    const float* __restrict__ bih = dir ? bih_r : bih_f;
    const float* __restrict__ bhh = dir ? bhh_r : bhh_f;

    const int rows[4] = {uc, 5 + uc, 10 + uc, 15 + uc};
    const float scl[4] = {-L2E, -L2E, T2E, -L2E};
    // x-weights as fp16 pairs matching the two 12B plane rows:
    // fwd plane pairs p=0..2: (w0,w1)(w2,w3)(w4,0)
    // bwd plane pairs p=3..5: (w5,w6)(w7,w8)(w9,0)
    v2h WX[4][6];
    float WH[4][5], BS[4];
#pragma unroll
    for (int gi = 0; gi < 4; gi++) {
        const int rr = rows[gi]; const float sc = scl[gi];
#pragma unroll
        for (int p = 0; p < 6; p++) {
            const int i0 = (p < 3) ? 2 * p : 2 * p - 1;   // 0,2,4,5,7,9
            const bool pad = (p == 2) || (p == 5);
            const float w0 = wih[rr * 10 + i0] * sc;
            const float w1 = pad ? 0.f : wih[rr * 10 + i0 + 1] * sc;
            WX[gi][p] = (v2h){(_Float16)w0, (_Float16)w1};
        }
#pragma unroll
        for (int k = 0; k < 5; k++) WH[gi][k] = whh[rr * 5 + k] * sc;
        BS[gi] = (bih[rr] + bhh[rr]) * sc;
    }

    float h[5] = {0.f, 0.f, 0.f, 0.f, 0.f};
    float cp = 0.f, hu_last = 0.f;

    const int t0 = dir ? (S_ - 1) : 0;          // this row's s at t=0
    const unsigned short* rpf = ws + ((size_t)t0 * B_ + b) * 6;
    const unsigned short* rpb = rpf + (size_t)S_ * B_ * 6;
    // out pointer starts at the first row phase 2 writes:
    // fwd: s = 256 (t=256); bwd: s = 255 (t=256 -> s=511-256).
    float* op = outbase + ((size_t)(dir ? 255 : 256) * B_ + b) * 10;
    const ptrdiff_t rst = dir ? -(ptrdiff_t)6 * B_ : (ptrdiff_t)6 * B_;
    const ptrdiff_t ost = dir ? -(ptrdiff_t)10 * B_ : (ptrdiff_t)10 * B_;

    // spill (phi1 steps 240..255 -> rows 0..15 of gtemp)
    unsigned short* gw = gtemp + (size_t)bid * 64 + l64;

    struct A4 { float a0, a1, a2, a3; };

    auto dots = [&](const v2h (&xin)[6]) -> A4 {
        A4 v;
        v.a0 = BS[0]; v.a1 = BS[1]; v.a2 = BS[2]; v.a3 = BS[3];
#pragma unroll
        for (int p = 0; p < 6; p++) {
            v.a0 = dot2h(xin[p], WX[0][p], v.a0);
            v.a1 = dot2h(xin[p], WX[1][p], v.a1);
            v.a2 = dot2h(xin[p], WX[2][p], v.a2);
            v.a3 = dot2h(xin[p], WX[3][p], v.a3);
        }
        return v;
    };

    auto cell = [&](A4 v) -> float {
#pragma unroll
        for (int k = 0; k < 5; k++) {
            v.a0 = fmaf(WH[0][k], h[k], v.a0);
            v.a1 = fmaf(WH[1][k], h[k], v.a1);
            v.a2 = fmaf(WH[2][k], h[k], v.a2);
            v.a3 = fmaf(WH[3][k], h[k], v.a3);
        }
        const float ig = rcp_(1.0f + exp2_(v.a0));
        const float fg = rcp_(1.0f + exp2_(v.a1));
        const float g2 = fmaf(-2.0f * T2E, rcp_(1.0f + exp2_(v.a2)), T2E);
        const float og = rcp_(1.0f + exp2_(v.a3));
        cp = fmaf(fg, cp, ig * g2);
        const float th = fmaf(-2.0f, rcp_(1.0f + exp2_(cp)), 1.0f);
        const float hu = og * th;
        hu_last = hu;
        return hu;
    };

    // broadcast within each 8-lane group via ds_swizzle:
    // lane' = (lane & 0x18) | k  ->  offset = 0x18 | (k<<5)
    auto bcast = [&](float hu) {
        const int v = __float_as_int(hu);
        h[0] = __int_as_float(__builtin_amdgcn_ds_swizzle(v, 0x18 | (0 << 5)));
        h[1] = __int_as_float(__builtin_amdgcn_ds_swizzle(v, 0x18 | (1 << 5)));
        h[2] = __int_as_float(__builtin_amdgcn_ds_swizzle(v, 0x18 | (2 << 5)));
        h[3] = __int_as_float(__builtin_amdgcn_ds_swizzle(v, 0x18 | (3 << 5)));
        h[4] = __int_as_float(__builtin_amdgcn_ds_swizzle(v, 0x18 | (4 << 5)));
    };

    auto ld = [&](v2h (&buf)[6]) {
        __builtin_memcpy(&buf[0], rpf, 12);
        __builtin_memcpy(&buf[3], rpb, 12);
        rpf += rst; rpb += rst;
        sbar();
    };

    // phase steps: dots -> ld(next) -> cell -> bcast -> stash/stores
    auto s1L = [&](v2h (&xb)[6], int t) {
        A4 a = dots(xb); ld(xb);
        const float hu = cell(a); bcast(hu);
        if (st) lt[t * 40 + r * 5 + u] = f2h(hu);
    };
    auto s1G = [&](v2h (&xb)[6]) {
        A4 a = dots(xb); ld(xb);
        const float hu = cell(a); bcast(hu);
        *gw = f2h(hu); gw += GSTR;
    };
    auto s2G = [&](v2h (&xb)[6], unsigned short pvs) {
        A4 a = dots(xb); ld(xb);
        const float pv = h2f(pvs);
        const float hu = cell(a); bcast(hu);
        if (st) { op[dir5 + u] = hu; op[5 - dir5 + u] = pv; }
        op += ost;
    };
    auto s2L = [&](v2h (&xb)[6], int t) {
        const float pv = h2f(lt[(511 - t) * 40 + psL]);
        A4 a = dots(xb); ld(xb);
        const float hu = cell(a); bcast(hu);
        if (st) { op[dir5 + u] = hu; op[5 - dir5 + u] = pv; }
        op += ost;
    };
    auto s2Ln = [&](v2h (&xb)[6], int t) {    // tail: no load
        const float pv = h2f(lt[(511 - t) * 40 + psL]);
        A4 a = dots(xb);
        const float hu = cell(a); bcast(hu);
        if (st) { op[dir5 + u] = hu; op[5 - dir5 + u] = pv; }
        op += ost;
    };

    v2h x0[6], x1[6], x2[6], x3[6], x4[6], x5[6], x6[6], x7[6];
    ld(x0); ld(x1); ld(x2); ld(x3); ld(x4); ld(x5); ld(x6); ld(x7);  // t=0..7

    // phi1a: t = 0..239 (LDS stash), loads 8..247
#pragma unroll 1
    for (int t = 0; t < TL; t += 8) {
        s1L(x0, t + 0); s1L(x1, t + 1); s1L(x2, t + 2); s1L(x3, t + 3);
        s1L(x4, t + 4); s1L(x5, t + 5); s1L(x6, t + 6); s1L(x7, t + 7);
    }
    // phi1b: t = 240..255 (global stash), loads 248..263
#pragma unroll 1
    for (int t = TL; t < 256; t += 8) {
        s1G(x0); s1G(x1); s1G(x2); s1G(x3);
        s1G(x4); s1G(x5); s1G(x6); s1G(x7);
    }
    // drain: spill rows (last written t=255) must be L2-visible before read.
    asm volatile("s_waitcnt vmcnt(0)" ::: "memory");
    // load ALL 16 spill partners upfront (rows 15..0 <-> t=256..271)
    const unsigned short* g0 = gtemp + (size_t)bid * 64 + psG;
    const unsigned short q15 = g0[(size_t)15 * GSTR];
    const unsigned short q14 = g0[(size_t)14 * GSTR];
    const unsigned short q13 = g0[(size_t)13 * GSTR];
    const unsigned short q12 = g0[(size_t)12 * GSTR];
    const unsigned short q11 = g0[(size_t)11 * GSTR];
    const unsigned short q10 = g0[(size_t)10 * GSTR];
    const unsigned short q9  = g0[(size_t)9  * GSTR];
    const unsigned short q8  = g0[(size_t)8  * GSTR];
    const unsigned short q7  = g0[(size_t)7  * GSTR];
    const unsigned short q6  = g0[(size_t)6  * GSTR];
    const unsigned short q5  = g0[(size_t)5  * GSTR];
    const unsigned short q4  = g0[(size_t)4  * GSTR];
    const unsigned short q3  = g0[(size_t)3  * GSTR];
    const unsigned short q2  = g0[(size_t)2  * GSTR];
    const unsigned short q1  = g0[(size_t)1  * GSTR];
    const unsigned short q0  = g0[0];
    // phi2a: t = 256..271 (partner from spill regs), loads 264..279
    s2G(x0, q15); s2G(x1, q14); s2G(x2, q13); s2G(x3, q12);
    s2G(x4, q11); s2G(x5, q10); s2G(x6, q9);  s2G(x7, q8);
    s2G(x0, q7);  s2G(x1, q6);  s2G(x2, q5);  s2G(x3, q4);
    s2G(x4, q3);  s2G(x5, q2);  s2G(x6, q1);  s2G(x7, q0);
    // phi2b: t = 272..503 (partner from LDS), loads 280..511
#pragma unroll 1
    for (int t = 272; t < 504; t += 8) {
        s2L(x0, t + 0); s2L(x1, t + 1); s2L(x2, t + 2); s2L(x3, t + 3);
        s2L(x4, t + 4); s2L(x5, t + 5); s2L(x6, t + 6); s2L(x7, t + 7);
    }
    // tail: t = 504..511, no more loads
    s2Ln(x0, 504); s2Ln(x1, 505); s2Ln(x2, 506); s2Ln(x3, 507);
    s2Ln(x4, 508); s2Ln(x5, 509); s2Ln(x6, 510); s2Ln(x7, 511);

    const size_t OUTE = (size_t)S_ * B_ * 10;
    float* hn = outbase + OUTE + ((size_t)(2 + dir) * B_ + b) * 5;
    float* cn = hn + (size_t)4 * B_ * 5;
    if (st) { hn[u] = hu_last; cn[u] = cp * IT2E; }
}

extern "C" void kernel_launch(void* const* d_in, const int* in_sizes, int n_in,
                              void* d_out, int out_size, void* d_ws, size_t ws_size,
                              hipStream_t stream) {
    const float* x       = (const float*)d_in[0];
    const float* wih_l0  = (const float*)d_in[1];
    const float* whh_l0  = (const float*)d_in[2];
    const float* bih_l0  = (const float*)d_in[3];
    const float* bhh_l0  = (const float*)d_in[4];
    const float* wih_l0r = (const float*)d_in[5];
    const float* whh_l0r = (const float*)d_in[6];
    const float* bih_l0r = (const float*)d_in[7];
    const float* bhh_l0r = (const float*)d_in[8];
    const float* wih_l1  = (const float*)d_in[9];
    const float* whh_l1  = (const float*)d_in[10];
    const float* bih_l1  = (const float*)d_in[11];
    const float* bhh_l1  = (const float*)d_in[12];
    const float* wih_l1r = (const float*)d_in[13];
    const float* whh_l1r = (const float*)d_in[14];
    const float* bih_l1r = (const float*)d_in[15];
    const float* bhh_l1r = (const float*)d_in[16];

    float* out = (float*)d_out;
    unsigned short* ws = (unsigned short*)d_ws;   // 2 planes * S*B*12B = 100.7 MB
    // phi1 spill: 16 rows * 2048 waves * 64 shorts = 4.2 MB, after ws planes
    unsigned short* gtemp = ws + (size_t)2 * S_ * B_ * 6;

    // layer0: 16384 (dir,row) sequences, 12 per wave -> 1366 single-wave blocks
    dim3 grid0(1366), block(64);
    lstm_layer0<<<grid0, block, 0, stream>>>(x,
        wih_l0, whh_l0, bih_l0, bhh_l0,
        wih_l0r, whh_l0r, bih_l0r, bhh_l0r,
        ws, out);
    // layer1: 4 b-values x 2 dirs per wave -> 2048 blocks = 2 waves/SIMD
    dim3 grid1(GD1);
    lstm_layer1<<<grid1, block, 0, stream>>>(ws,
        wih_l1, whh_l1, bih_l1, bhh_l1,
        wih_l1r, whh_l1r, bih_l1r, bhh_l1r,
        out, gtemp);
}